// Round 12
// baseline (326.908 us; speedup 1.0000x reference)
//
#include <hip/hip_runtime.h>
#include <hip/hip_bf16.h>

typedef unsigned short u16;
typedef __attribute__((ext_vector_type(8))) short bfrag;   // 8 bf16 = 4 VGPR (MFMA A/B frag)
typedef __attribute__((ext_vector_type(4))) float f32x4;   // MFMA C/D frag
typedef __attribute__((ext_vector_type(8))) unsigned short us8;
typedef __attribute__((ext_vector_type(4))) unsigned short us4;

__device__ __forceinline__ u16 f2bf(float f) {
  union { float f; unsigned int u; } x; x.f = f;
  unsigned int r = x.u + 0x7fffu + ((x.u >> 16) & 1u);
  return (u16)(r >> 16);
}
__device__ __forceinline__ float bf2f(u16 u) {
  union { unsigned int u; float f; } x; x.u = ((unsigned int)u) << 16;
  return x.f;
}

__device__ __forceinline__ void gld16(const void* g, void* l) {
  __builtin_amdgcn_global_load_lds((const __attribute__((address_space(1))) void*)g,
                                   (__attribute__((address_space(3))) void*)l, 16, 0, 0);
}

// ---------------------------------------------------------------------------
// Kernel 0: transpose + convert weights: W[k][n] f32 (1024x1024) -> Wt[n][k] bf16
// ---------------------------------------------------------------------------
__global__ __launch_bounds__(256) void transpose_w(const float* __restrict__ W0,
                                                   const float* __restrict__ W1,
                                                   const float* __restrict__ W2,
                                                   u16* __restrict__ T0,
                                                   u16* __restrict__ T1,
                                                   u16* __restrict__ T2) {
  const float* W = (blockIdx.z == 0) ? W0 : ((blockIdx.z == 1) ? W1 : W2);
  u16* T = (blockIdx.z == 0) ? T0 : ((blockIdx.z == 1) ? T1 : T2);
  __shared__ u16 tile[64][72];
  const int t = threadIdx.x;
  const int rr = t >> 4;
  const int cc = (t & 15) * 4;
  const int kbase = blockIdx.y * 64, nbase = blockIdx.x * 64;
#pragma unroll
  for (int j = 0; j < 4; ++j) {
    int kl = rr + j * 16;
    float4 v = *(const float4*)(W + (size_t)(kbase + kl) * 1024 + nbase + cc);
    tile[kl][cc + 0] = f2bf(v.x);
    tile[kl][cc + 1] = f2bf(v.y);
    tile[kl][cc + 2] = f2bf(v.z);
    tile[kl][cc + 3] = f2bf(v.w);
  }
  __syncthreads();
#pragma unroll
  for (int j = 0; j < 4; ++j) {
    int nl = rr + j * 16;
    us4 o;
    o[0] = tile[cc + 0][nl];
    o[1] = tile[cc + 1][nl];
    o[2] = tile[cc + 2][nl];
    o[3] = tile[cc + 3][nl];
    *(us4*)(T + (size_t)(nbase + nl) * 1024 + kbase + cc) = o;
  }
}

// ---------------------------------------------------------------------------
// Kernel 1: f32 -> bf16 convert (vectorized, grid-stride)
// ---------------------------------------------------------------------------
__global__ __launch_bounds__(256) void cvt_bf16(const float* __restrict__ src,
                                                u16* __restrict__ dst, int n8) {
  int i = blockIdx.x * blockDim.x + threadIdx.x;
  const int stride = gridDim.x * blockDim.x;
  for (; i < n8; i += stride) {
    const float4* p = (const float4*)(src + (size_t)i * 8);
    float4 v0 = p[0], v1 = p[1];
    us8 o;
    o[0] = f2bf(v0.x); o[1] = f2bf(v0.y); o[2] = f2bf(v0.z); o[3] = f2bf(v0.w);
    o[4] = f2bf(v1.x); o[5] = f2bf(v1.y); o[6] = f2bf(v1.z); o[7] = f2bf(v1.w);
    *(us8*)(dst + (size_t)i * 8) = o;
  }
}

// ---------------------------------------------------------------------------
// Kernel 2: 256x256-tile BT GEMM, BK=64, 512 threads (8 waves, 2M x 4N).
//   8-phase counted-vmcnt schedule (session-best rate: ~2.1 us/8.4MF tile on
//   projections), T2 XOR-swizzled staging, T5 setprio.
// MAP (block mapping):
//   0 = proj panel-share: grid (4,64); groups of 8 ids share by, sweep bx.
//   1 = scores supertile: grid (512); id = xcd|j|t -> 4x4 block supertile,
//       per-XCD working set = 4 MB (L2-fit), mask load spread across XCDs.
//   2 = PV supertile: grid (256); same idea on the (4 x 8 x 8) PV grid.
// OUT: 0 = bf16 + bias | 1 = bf16 * 1/32 (early-exit bcol>=len) |
//      2 = lvt-transposed + bias | 3 = f32 (K truncated at ceil64(len))
// C = A[M][K](bf16) x B[N][K]^T(bf16).
// ---------------------------------------------------------------------------
template <int OUT, int MAP>
__global__ __launch_bounds__(512, 2) void gemm256(const u16* __restrict__ gA,
                                                  const u16* __restrict__ gB,
                                                  const float* __restrict__ bias,
                                                  void* __restrict__ outp,
                                                  int K, int ldc,
                                                  size_t aStride, size_t bStride,
                                                  size_t cStride,
                                                  const int* __restrict__ seq) {
  __shared__ u16 lds[65536];   // A: [0,32768) (2 bufs), B: [32768,65536)
  const int tid = threadIdx.x;

  int bx, by, bz;
  if constexpr (MAP == 0) {
    const int id = blockIdx.x + gridDim.x * blockIdx.y;
    bx = (id >> 3) & 3; by = (id & 7) + 8 * (id >> 5); bz = 0;
  } else if constexpr (MAP == 1) {
    // scores: 512 ids = xcd(3b) | j(4b) | t(2b); S = xcd + 8t in [0,32)
    const int id = blockIdx.x;
    const int j = (id >> 3) & 15;
    const int S = (id & 7) + 8 * (id >> 7);
    bz = S >> 2;
    const int s4 = S & 3;
    by = (s4 >> 1) * 4 + (j >> 2);
    bx = (s4 & 1) * 4 + (j & 3);
  } else {
    // PV: 256 ids = xcd(3b) | j(4b) | t(1b); S = xcd + 8t in [0,16)
    const int id = blockIdx.x;
    const int j = (id >> 3) & 15;
    const int S = (id & 7) + 8 * (id >> 7);
    bz = S >> 1;
    by = (S & 1) * 4 + (j >> 2);
    bx = j & 3;
  }

  const u16* A = gA + (size_t)bz * aStride;
  const u16* B = gB + (size_t)bz * bStride;
  const int brow = by * 256, bcol = bx * 256;

  const int NT = K >> 6;
  int NTe = NT;
  if constexpr (OUT == 1) {
    if (bcol >= seq[bz]) return;   // masked-out score tile: never read downstream
  }
  if constexpr (OUT == 3) {
    const int len = seq[bz];
    const int nt2 = (len + 63) >> 6;  // probs exactly 0 beyond ceil64(len)
    NTe = nt2 < NT ? nt2 : NT;
  }

  const int wv = tid >> 6, l = tid & 63;
  const int wm = wv >> 2, wn = wv & 3;
  const int fr = l & 15, fq = l >> 4;
  const int g0 = (fq ^ (fr & 7)) * 8;          // u16 offset of kk=0 granule
  const int g1 = ((4 + fq) ^ (fr & 7)) * 8;    // kk=1

  const int srow = tid >> 3;
  const int sg = (tid & 7) ^ (srow & 7);
  const u16* aS = A + (size_t)(brow + srow) * K + sg * 8;
  const u16* bS = B + (size_t)(bcol + srow) * K + sg * 8;
  u16* const dA = lds + wv * 512;
  u16* const dB = lds + 32768 + wv * 512;

  f32x4 acc[8][4] = {};

  auto stA = [&](int tile, int c, int buf) {
    gld16(aS + (size_t)tile * 64 + (size_t)c * 64 * K, dA + buf * 16384 + c * 4096);
  };
  auto stB = [&](int tile, int c, int buf) {
    gld16(bS + (size_t)tile * 64 + (size_t)c * 64 * K, dB + buf * 16384 + c * 4096);
  };

  // ---- prologue: all 8 units of tile 0 -> buf0; 6 units of tile 1 -> buf1
#pragma unroll
  for (int c = 0; c < 4; ++c) stA(0, c, 0);
#pragma unroll
  for (int c = 0; c < 4; ++c) stB(0, c, 0);
  if (NTe > 1) {
    stA(1, 0, 1); stA(1, 2, 1);
    stB(1, 0, 1); stB(1, 1, 1); stB(1, 2, 1); stB(1, 3, 1);
  }

  for (int t = 0; t < NTe; ++t) {
    const int cur = t & 1;
    const u16* At = lds + cur * 16384;
    const u16* Bt = lds + 32768 + cur * 16384;

    // entry: all of tile t landed when <=6 younger loads outstanding
    if (t + 1 < NTe) asm volatile("s_waitcnt vmcnt(6)" ::: "memory");
    else             asm volatile("s_waitcnt vmcnt(0)" ::: "memory");
    __builtin_amdgcn_s_barrier();

    bfrag a[4][2], b[2][2][2];

    // ---- q0: read A(mh0) + B(nh0); stage A1,A3 of t+1 -> buf cur^1
#pragma unroll
    for (int m = 0; m < 4; ++m) {
      const u16* p = At + (wm * 128 + m * 16 + fr) * 64;
      a[m][0] = *(const bfrag*)(p + g0);
      a[m][1] = *(const bfrag*)(p + g1);
    }
#pragma unroll
    for (int n = 0; n < 2; ++n) {
      const u16* p = Bt + (wn * 64 + n * 16 + fr) * 64;
      b[0][n][0] = *(const bfrag*)(p + g0);
      b[0][n][1] = *(const bfrag*)(p + g1);
    }
    if (t + 1 < NTe) { stA(t + 1, 1, cur ^ 1); stA(t + 1, 3, cur ^ 1); }
    __builtin_amdgcn_s_barrier();
    asm volatile("s_waitcnt lgkmcnt(0)" ::: "memory");
    __builtin_amdgcn_sched_barrier(0);
    __builtin_amdgcn_s_setprio(1);
#pragma unroll
    for (int n = 0; n < 2; ++n)
#pragma unroll
      for (int m = 0; m < 4; ++m) {
        acc[m][n] = __builtin_amdgcn_mfma_f32_16x16x32_bf16(a[m][0], b[0][n][0], acc[m][n], 0, 0, 0);
        acc[m][n] = __builtin_amdgcn_mfma_f32_16x16x32_bf16(a[m][1], b[0][n][1], acc[m][n], 0, 0, 0);
      }
    __builtin_amdgcn_s_setprio(0);
    __builtin_amdgcn_s_barrier();

    // ---- q1: read B(nh1); stage A0,A2 of t+2 -> buf cur
#pragma unroll
    for (int n = 0; n < 2; ++n) {
      const u16* p = Bt + (wn * 64 + 32 + n * 16 + fr) * 64;
      b[1][n][0] = *(const bfrag*)(p + g0);
      b[1][n][1] = *(const bfrag*)(p + g1);
    }
    if (t + 2 < NTe) { stA(t + 2, 0, cur); stA(t + 2, 2, cur); }
    __builtin_amdgcn_s_barrier();
    asm volatile("s_waitcnt lgkmcnt(0)" ::: "memory");
    __builtin_amdgcn_sched_barrier(0);
    __builtin_amdgcn_s_setprio(1);
#pragma unroll
    for (int n = 0; n < 2; ++n)
#pragma unroll
      for (int m = 0; m < 4; ++m) {
        acc[m][2 + n] = __builtin_amdgcn_mfma_f32_16x16x32_bf16(a[m][0], b[1][n][0], acc[m][2 + n], 0, 0, 0);
        acc[m][2 + n] = __builtin_amdgcn_mfma_f32_16x16x32_bf16(a[m][1], b[1][n][1], acc[m][2 + n], 0, 0, 0);
      }
    __builtin_amdgcn_s_setprio(0);
    __builtin_amdgcn_s_barrier();

    // ---- q2: read A(mh1); stage B0,B1 of t+2 -> buf cur
#pragma unroll
    for (int m = 0; m < 4; ++m) {
      const u16* p = At + (wm * 128 + 64 + m * 16 + fr) * 64;
      a[m][0] = *(const bfrag*)(p + g0);
      a[m][1] = *(const bfrag*)(p + g1);
    }
    if (t + 2 < NTe) { stB(t + 2, 0, cur); stB(t + 2, 1, cur); }
    __builtin_amdgcn_s_barrier();
    asm volatile("s_waitcnt lgkmcnt(0)" ::: "memory");
    __builtin_amdgcn_sched_barrier(0);
    __builtin_amdgcn_s_setprio(1);
#pragma unroll
    for (int n = 0; n < 2; ++n)
#pragma unroll
      for (int m = 0; m < 4; ++m) {
        acc[4 + m][n] = __builtin_amdgcn_mfma_f32_16x16x32_bf16(a[m][0], b[0][n][0], acc[4 + m][n], 0, 0, 0);
        acc[4 + m][n] = __builtin_amdgcn_mfma_f32_16x16x32_bf16(a[m][1], b[0][n][1], acc[4 + m][n], 0, 0, 0);
      }
    __builtin_amdgcn_s_setprio(0);
    __builtin_amdgcn_s_barrier();

    // ---- q3: stage B2,B3 of t+2 -> buf cur; MFMA quadrant (1,1)
    if (t + 2 < NTe) { stB(t + 2, 2, cur); stB(t + 2, 3, cur); }
    __builtin_amdgcn_s_setprio(1);
#pragma unroll
    for (int n = 0; n < 2; ++n)
#pragma unroll
      for (int m = 0; m < 4; ++m) {
        acc[4 + m][2 + n] = __builtin_amdgcn_mfma_f32_16x16x32_bf16(a[m][0], b[1][n][0], acc[4 + m][2 + n], 0, 0, 0);
        acc[4 + m][2 + n] = __builtin_amdgcn_mfma_f32_16x16x32_bf16(a[m][1], b[1][n][1], acc[4 + m][2 + n], 0, 0, 0);
      }
    __builtin_amdgcn_s_setprio(0);
    __builtin_amdgcn_s_barrier();
  }

  // epilogue
#pragma unroll
  for (int mg = 0; mg < 8; ++mg) {
    const int r0 = brow + wm * 128 + mg * 16 + fq * 4;
#pragma unroll
    for (int n = 0; n < 4; ++n) {
      const int c = bcol + wn * 64 + n * 16 + fr;
      f32x4 vv = acc[mg][n];
      if constexpr (OUT == 0) {
        float bb = bias[c];
        u16* C = (u16*)outp;
#pragma unroll
        for (int j = 0; j < 4; ++j) C[(size_t)(r0 + j) * ldc + c] = f2bf(vv[j] + bb);
      } else if constexpr (OUT == 1) {
        u16* C = (u16*)outp + (size_t)bz * cStride;
#pragma unroll
        for (int j = 0; j < 4; ++j) C[(size_t)(r0 + j) * ldc + c] = f2bf(vv[j] * 0.03125f);
      } else if constexpr (OUT == 2) {
        float bb = bias[c];
        const int bz2 = r0 >> 11, mm = r0 & 2047;
        us4 o;
#pragma unroll
        for (int j = 0; j < 4; ++j) o[j] = f2bf(vv[j] + bb);
        *(us4*)((u16*)outp + ((size_t)bz2 * 1024 + c) * 2048 + mm) = o;
      } else {
        float* C = (float*)outp + (size_t)bz * cStride;
#pragma unroll
        for (int j = 0; j < 4; ++j) C[(size_t)(r0 + j) * ldc + c] = vv[j];
      }
    }
  }
}

// ---------------------------------------------------------------------------
// Kernel 3: masked softmax over m, in place on probs (bf16). One block per row.
// ---------------------------------------------------------------------------
__global__ __launch_bounds__(256) void softmax_mask(u16* __restrict__ probs,
                                                    const int* __restrict__ seq) {
  const int bid = blockIdx.x;
  const int b = bid >> 11, n = bid & 2047;
  const int len = seq[b];
  const int len64 = (len + 63) & ~63;
  u16* row = probs + ((size_t)b * 2048 + n) * 2048;
  const int t = threadIdx.x;
  const int w = t >> 6, l = t & 63;

  us8 sv = {};
  if (t * 8 < len) sv = *(const us8*)(row + t * 8);
  float vals[8];
  float vmax = -1e30f;
#pragma unroll
  for (int e = 0; e < 8; ++e) {
    int m = t * 8 + e;
    float x = bf2f(sv[e]);
    vals[e] = (m < len) ? x : -1e30f;
    vmax = fmaxf(vmax, vals[e]);
  }
#pragma unroll
  for (int o = 32; o > 0; o >>= 1) vmax = fmaxf(vmax, __shfl_xor(vmax, o, 64));
  __shared__ float sm[4], ss[4];
  if (l == 0) sm[w] = vmax;
  __syncthreads();
  vmax = fmaxf(fmaxf(sm[0], sm[1]), fmaxf(sm[2], sm[3]));

  float ev[8];
  float sum = 0.f;
#pragma unroll
  for (int e = 0; e < 8; ++e) {
    int m = t * 8 + e;
    float p = (m < len) ? __expf(vals[e] - vmax) : 0.f;
    ev[e] = p;
    sum += p;
  }
#pragma unroll
  for (int o = 32; o > 0; o >>= 1) sum += __shfl_xor(sum, o, 64);
  if (l == 0) ss[w] = sum;
  __syncthreads();
  sum = ss[0] + ss[1] + ss[2] + ss[3];
  float inv = 1.f / sum;
  if (t * 8 < len64) {
    us8 ov;
#pragma unroll
    for (int e = 0; e < 8; ++e) ov[e] = f2bf(ev[e] * inv);
    *(us8*)(row + t * 8) = ov;
  }
}

// ---------------------------------------------------------------------------
extern "C" void kernel_launch(void* const* d_in, const int* in_sizes, int n_in,
                              void* d_out, int out_size, void* d_ws, size_t ws_size,
                              hipStream_t stream) {
  const float* q   = (const float*)d_in[0];
  const float* k   = (const float*)d_in[1];
  const float* v   = (const float*)d_in[2];
  const int*   seq = (const int*)d_in[3];
  const float* Wq  = (const float*)d_in[4];
  const float* bq  = (const float*)d_in[5];
  const float* Wk  = (const float*)d_in[6];
  const float* bk  = (const float*)d_in[7];
  const float* Wv  = (const float*)d_in[8];
  const float* bv  = (const float*)d_in[9];
  float* out = (float*)d_out;

  // workspace layout (u16 elements) — ~166 MB:
  //   wt: 3 x 1M | lq/lk/lvt: 3 x 16M | probs: 33.5M (cvt buffer aliased in)
  u16* ws = (u16*)d_ws;
  u16* wtq = ws;
  u16* wtk = wtq + (size_t)1024 * 1024;
  u16* wtv = wtk + (size_t)1024 * 1024;
  u16* lq  = wtv + (size_t)1024 * 1024;
  u16* lk  = lq + (size_t)16384 * 1024;
  u16* lvt = lk + (size_t)16384 * 1024;
  u16* probs = lvt + (size_t)16384 * 1024;
  u16* cbuf = probs;          // 16M u16 convert buffer (dead before scores)

  const size_t S21 = (size_t)2048 * 1024;   // per-batch stride, 2048x1024
  const size_t S22 = (size_t)2048 * 2048;   // per-batch stride, 2048x2048

  transpose_w<<<dim3(16, 16, 3), 256, 0, stream>>>(Wq, Wk, Wv, wtq, wtk, wtv);

  // Q projection
  cvt_bf16<<<dim3(2048), 256, 0, stream>>>(q, cbuf, 2097152);
  gemm256<0, 0><<<dim3(4, 64), 512, 0, stream>>>(cbuf, wtq, bq, lq, 1024, 1024, 0, 0, 0, nullptr);
  // K projection
  cvt_bf16<<<dim3(2048), 256, 0, stream>>>(k, cbuf, 2097152);
  gemm256<0, 0><<<dim3(4, 64), 512, 0, stream>>>(cbuf, wtk, bk, lk, 1024, 1024, 0, 0, 0, nullptr);
  // V projection -> transposed lvt[b][o][m]
  cvt_bf16<<<dim3(2048), 256, 0, stream>>>(v, cbuf, 2097152);
  gemm256<2, 0><<<dim3(4, 64), 512, 0, stream>>>(cbuf, wtv, bv, lvt, 1024, 1024, 0, 0, 0, nullptr);

  // scores = lq @ lk^T / 32  (supertile map, masked tiles skipped)
  gemm256<1, 1><<<dim3(512), 512, 0, stream>>>(lq, lk, nullptr, probs, 1024, 2048,
                                               S21, S21, S22, seq);
  // masked softmax in place
  softmax_mask<<<dim3(16384), 256, 0, stream>>>(probs, seq);
  // out = probs @ lv  (supertile map, lvt B^T layout, K truncated)
  gemm256<3, 2><<<dim3(256), 512, 0, stream>>>(probs, lvt, nullptr, out, 2048, 1024,
                                               S22, S21, S21, seq);
}